// Round 6
// baseline (101.126 us; speedup 1.0000x reference)
//
#include <hip/hip_runtime.h>

// ---------------------------------------------------------------------------
// R12: two-kernel shell (R0's 97.2 structure — fused falsified twice at +3us
// from per-block precompute replication) + the R11-validated LDS dup-pair
// pk loop in q_main:
//  - q_precompute writes the dup-pair table (24 f/row, {c,c} pairs) to d_ws.
//  - q_main stages 788 floats -> LDS with one float4/thread (t<197), hidden
//    under x-loads + trig; then the l-loop reads {c,c} pairs via ds_read_b64
//    straight into v_pk_fma_f32 operands: 48 VALU + 11 DS slots per l vs
//    R0's ~120 scalar VALU slots per l.
// Model: dur = 2x~44us unconditional ws fills + pre ~1.6 + q_main.
// Predict q_main 5.5-6.5us -> dur 94.5-96. If >=97.2: revert + declare.
// ---------------------------------------------------------------------------

typedef float f32x2 __attribute__((ext_vector_type(2)));

static __device__ __forceinline__ f32x2 pkfma(f32x2 a, f32x2 b, f32x2 c) {
    f32x2 d;
    asm("v_pk_fma_f32 %0, %1, %2, %3" : "=v"(d) : "v"(a), "v"(b), "v"(c));
    return d;
}
static __device__ __forceinline__ f32x2 pkmul(f32x2 a, f32x2 b) {
    f32x2 d;
    asm("v_pk_mul_f32 %0, %1, %2" : "=v"(d) : "v"(a), "v"(b));
    return d;
}
static __device__ __forceinline__ f32x2 splat2(float v) {
    f32x2 r; r.x = v; r.y = v; return r;
}

#define INV_2PI 0.15915494309189535f

__global__ __launch_bounds__(64) void q_precompute(
    const float* __restrict__ theta,
    const float* __restrict__ W1,   // (8,32)
    const float* __restrict__ b1,   // (32,)
    const float* __restrict__ W2,   // (32,2)
    const float* __restrict__ b2,   // (2,)
    float* __restrict__ tab)        // 32 rows * 24 floats (dup pairs) + [768..769]=b2
{
    __shared__ float Ure[8][8];
    __shared__ float Uim[8][8];
    const int t = threadIdx.x;

    if (t < 8) {
        float cr[8], ci[8];
        #pragma unroll
        for (int r = 0; r < 8; ++r) { cr[r] = (r == t) ? 1.f : 0.f; ci[r] = 0.f; }

        auto rxmix = [&](int a, int b, float c_, float s_) {   // RX pair
            float ar = cr[a], ai = ci[a], br = cr[b], bi = ci[b];
            cr[a] = c_*ar + s_*bi;   ci[a] = c_*ai - s_*br;
            cr[b] = s_*ai + c_*br;   ci[b] = -s_*ar + c_*bi;
        };
        auto rymix = [&](int a, int b, float c_, float s_) {   // RY pair
            float ar = cr[a], ai = ci[a], br = cr[b], bi = ci[b];
            cr[a] = c_*ar - s_*br;   ci[a] = c_*ai - s_*bi;
            cr[b] = s_*ar + c_*br;   ci[b] = s_*ai + c_*bi;
        };
        auto zmul = [&](int r, float u, float v) {             // row *= (u+iv)
            float xr = cr[r], xi = ci[r];
            cr[r] = xr*u - xi*v;  ci[r] = xr*v + xi*u;
        };
        auto hsin = [&](float a) { return __builtin_amdgcn_sinf(a * (0.5f*INV_2PI)); };
        auto hcos = [&](float a) { return __builtin_amdgcn_cosf(a * (0.5f*INV_2PI)); };

        float c, s;
        // index = 4*i0 + 2*i1 + i2  (wire0 = MSB)
        c = hcos(theta[0]); s = hsin(theta[0]);                 // RX wire0
        rxmix(0,4,c,s); rxmix(1,5,c,s); rxmix(2,6,c,s); rxmix(3,7,c,s);
        c = hcos(theta[1]); s = hsin(theta[1]);                 // RY wire1
        rymix(0,2,c,s); rymix(1,3,c,s); rymix(4,6,c,s); rymix(5,7,c,s);
        c = hcos(theta[2]); s = hsin(theta[2]);                 // RZ wire2
        #pragma unroll
        for (int r = 0; r < 8; ++r) zmul(r, c, (r & 1) ? s : -s);
        c = hcos(theta[3]); s = hsin(theta[3]);                 // CRX 0->1
        rxmix(4,6,c,s); rxmix(5,7,c,s);
        c = hcos(theta[4]); s = hsin(theta[4]);                 // RY wire2
        rymix(0,1,c,s); rymix(2,3,c,s); rymix(4,5,c,s); rymix(6,7,c,s);
        c = hcos(theta[5]); s = hsin(theta[5]);                 // RX wire1
        rxmix(0,2,c,s); rxmix(1,3,c,s); rxmix(4,6,c,s); rxmix(5,7,c,s);
        c = hcos(theta[6]); s = hsin(theta[6]);                 // CRX 1->2
        rxmix(2,3,c,s); rxmix(6,7,c,s);
        c = hcos(theta[7]); s = hsin(theta[7]);                 // RZ wire0
        #pragma unroll
        for (int r = 0; r < 8; ++r) zmul(r, c, (r < 4) ? -s : s);

        #pragma unroll
        for (int r = 0; r < 8; ++r) { Ure[r][t] = cr[r]; Uim[r][t] = ci[r]; }
    }
    __syncthreads();   // single wave: cheap

    if (t < 32) {
        // W[:,m] = U[:,col(m)] * phase, col = {0,2,4,6}, phase = {1,1,-i,-i}
        float Wre[8][4], Wim[8][4];
        #pragma unroll
        for (int j = 0; j < 8; ++j) {
            Wre[j][0] =  Ure[j][0]; Wim[j][0] =  Uim[j][0];
            Wre[j][1] =  Ure[j][2]; Wim[j][1] =  Uim[j][2];
            Wre[j][2] =  Uim[j][4]; Wim[j][2] = -Ure[j][4];
            Wre[j][3] =  Uim[j][6]; Wim[j][3] = -Ure[j][6];
        }
        float Q[4][4];
        #pragma unroll
        for (int m = 0; m < 4; ++m)
            #pragma unroll
            for (int n = 0; n < 4; ++n) Q[m][n] = 0.f;
        #pragma unroll
        for (int j = 0; j < 8; ++j) {
            float w = W1[j*32 + t];
            #pragma unroll
            for (int m = 0; m < 4; ++m)
                #pragma unroll
                for (int n = 0; n < 4; ++n)
                    Q[m][n] = fmaf(w, Wre[j][m]*Wre[j][n] + Wim[j][m]*Wim[j][n], Q[m][n]);
        }
        float R[3][3];
        R[0][0] = Q[0][0];
        R[0][1] = Q[0][1] + Q[1][0];
        R[0][2] = Q[1][1];
        R[1][0] = Q[0][2] + Q[2][0];
        R[1][1] = Q[0][3] + Q[1][2] + Q[2][1] + Q[3][0];
        R[1][2] = Q[1][3] + Q[3][1];
        R[2][0] = Q[2][2];
        R[2][1] = Q[2][3] + Q[3][2];
        R[2][2] = Q[3][3];
        float P[3][3];
        #pragma unroll
        for (int b = 0; b < 3; ++b) {
            P[0][b] = 0.5f*(R[0][b] + R[2][b]);
            P[1][b] = 0.5f*(R[0][b] - R[2][b]);
            P[2][b] = 0.5f*R[1][b];
        }
        float T[3][3];
        #pragma unroll
        for (int si = 0; si < 3; ++si) {
            T[si][0] = 0.5f*(P[si][0] + P[si][2]);
            T[si][1] = 0.5f*(P[si][0] - P[si][2]);
            T[si][2] = 0.5f*P[si][1];
        }
        // Duplicated-pair row: pair p at floats [2p, 2p+1].
        // p: 0=T01 1=T02 2=T10 3=T20 4=T11 5=T12 6=T21 7=T22 8=bias 9=w0 10=w1
        float* row = tab + t*24;
        row[0]  = row[1]  = T[0][1];
        row[2]  = row[3]  = T[0][2];
        row[4]  = row[5]  = T[1][0];
        row[6]  = row[7]  = T[2][0];
        row[8]  = row[9]  = T[1][1];
        row[10] = row[11] = T[1][2];
        row[12] = row[13] = T[2][1];
        row[14] = row[15] = T[2][2];
        row[16] = row[17] = b1[t] + T[0][0];
        row[18] = row[19] = W2[t*2+0];
        row[20] = row[21] = W2[t*2+1];
        row[22] = row[23] = 0.f;
    }
    if (t == 0) { tab[768] = b2[0]; tab[769] = b2[1]; }
}

__global__ __launch_bounds__(256) void q_main(
    const float* __restrict__ x,
    const float* __restrict__ tab,
    float* __restrict__ out,
    int B)
{
    // LDS copy of the table: 788 floats = 197 float4 (3152 B)
    __shared__ __align__(16) float tabL[788];

    const int t  = threadIdx.x;
    const int bb = blockIdx.x * 2048;           // 8 elems/thread * 256 thr
    const int e0 = bb + t;

    // 1) x loads issued first (in flight during staging + trig)
    float xs0[8], xs1[8];
    #pragma unroll
    for (int k = 0; k < 8; ++k) {
        int e = e0 + k*256;
        e = (e < B) ? e : (B - 1);              // clamp: tail reads dup element
        xs0[k] = x[e*3 + 0];
        xs1[k] = x[e*3 + 1];
    }

    // 2) stage table global->LDS: one float4 per thread (t<197)
    if (t < 197) {
        const float4 v = reinterpret_cast<const float4*>(tab)[t];
        reinterpret_cast<float4*>(tabL)[t] = v;
    }

    // 3) trig + products (independent of table; overlaps staging latency)
    f32x2 c0v[4], s0v[4], c1v[4], s1v[4], pcc[4], pcs[4], psc[4], pss[4];
    #pragma unroll
    for (int g = 0; g < 4; ++g) {
        #pragma unroll
        for (int j = 0; j < 2; ++j) {
            const int k = 2*g + j;
            const float r0 = xs0[k] * INV_2PI;
            const float r1 = xs1[k] * INV_2PI;
            s0v[g][j] = __builtin_amdgcn_sinf(r0);
            c0v[g][j] = __builtin_amdgcn_cosf(r0);
            s1v[g][j] = __builtin_amdgcn_sinf(r1);
            c1v[g][j] = __builtin_amdgcn_cosf(r1);
        }
        pcc[g] = pkmul(c0v[g], c1v[g]);
        pcs[g] = pkmul(c0v[g], s1v[g]);
        psc[g] = pkmul(s0v[g], c1v[g]);
        pss[g] = pkmul(s0v[g], s1v[g]);
    }
    __syncthreads();   // table staged

    const float b2a = tabL[768], b2b = tabL[769];
    f32x2 a0v[4], a1v[4];
    #pragma unroll
    for (int g = 0; g < 4; ++g) { a0v[g] = splat2(b2a); a1v[g] = splat2(b2b); }
    const f32x2 zero2 = splat2(0.f);

    // 4) l-loop: ds_read_b64 {c,c} pairs -> direct v_pk_fma_f32 operands.
    //    Per l: 11 ds_read_b64 + 40 v_pk_fma + 8 v_max (48 VALU slots).
    const f32x2* Tp = reinterpret_cast<const f32x2*>(tabL);
    #pragma unroll 2
    for (int l = 0; l < 32; ++l) {
        const int L = l*12;
        const f32x2 cT01 = Tp[L+0];
        const f32x2 cT02 = Tp[L+1];
        const f32x2 cT10 = Tp[L+2];
        const f32x2 cT20 = Tp[L+3];
        const f32x2 cT11 = Tp[L+4];
        const f32x2 cT12 = Tp[L+5];
        const f32x2 cT21 = Tp[L+6];
        const f32x2 cT22 = Tp[L+7];
        const f32x2 vb   = Tp[L+8];   // {bias,bias} pair, no splat
        const f32x2 cw0  = Tp[L+9];
        const f32x2 cw1  = Tp[L+10];
        #pragma unroll
        for (int g = 0; g < 4; ++g) {
            f32x2 h = pkfma(cT01, c1v[g], vb);
            h = pkfma(cT02, s1v[g], h);
            h = pkfma(cT10, c0v[g], h);
            h = pkfma(cT20, s0v[g], h);
            h = pkfma(cT11, pcc[g], h);
            h = pkfma(cT12, pcs[g], h);
            h = pkfma(cT21, psc[g], h);
            h = pkfma(cT22, pss[g], h);
            h = __builtin_elementwise_max(h, zero2);   // 2x v_max_f32
            a0v[g] = pkfma(cw0, h, a0v[g]);
            a1v[g] = pkfma(cw1, h, a1v[g]);
        }
    }

    // 5) coalesced stores, predicated for the tail
    f32x2* O2 = (f32x2*)out;
    #pragma unroll
    for (int k = 0; k < 8; ++k) {
        const int e = e0 + k*256;
        if (e < B) {
            f32x2 o; o.x = a0v[k>>1][k&1]; o.y = a1v[k>>1][k&1];
            O2[e] = o;
        }
    }
}

extern "C" void kernel_launch(void* const* d_in, const int* in_sizes, int n_in,
                              void* d_out, int out_size, void* d_ws, size_t ws_size,
                              hipStream_t stream) {
    const float* x     = (const float*)d_in[0];
    const float* theta = (const float*)d_in[1];
    const float* W1    = (const float*)d_in[2];
    const float* b1    = (const float*)d_in[3];
    const float* W2    = (const float*)d_in[4];
    const float* b2    = (const float*)d_in[5];
    float* out = (float*)d_out;
    float* tab = (float*)d_ws;

    const int B = in_sizes[0] / 3;

    q_precompute<<<1, 64, 0, stream>>>(theta, W1, b1, W2, b2, tab);

    const int blocks = (B + 2047) / 2048;       // 8 elems/thread * 256 thr
    q_main<<<blocks, 256, 0, stream>>>(x, tab, out, B);
}

// Round 8
// 97.651 us; speedup vs baseline: 1.0356x; 1.0356x over previous
//
#include <hip/hip_runtime.h>

// ---------------------------------------------------------------------------
// R14 = RESUBMIT of R13 (byte-equivalent to R0, best measured: 97.2us).
// R7(round) failed with a pytest core dump — infra flake, not kernel: this
// exact source passed in Round 0 (97.2us, absmax 9.8e-4). Kernel is
// deterministic (no atomics, block-independent writes), so pass/fail cannot
// be data-dependent.
// Session findings (R7 measurement round + R2/R10/R11/R12 probes):
//  - Timed iter = 2x ~44us UNCONDITIONAL ws-poison fills (~88us, HBM-bound at
//    75-79% peak; present even when d_ws is never touched) + precompute ~1.6
//    + q_main ~7.6us. The fills are the floor; not addressable from kernel.
//  - q_main's l-loop is VALU-issue-bound (~0.76us/pass marginal, R7 x16).
//    Alternative coefficient-delivery schemes all measured <= baseline:
//    SGPR-broadcast pk loop (R10, +1.3), fused+LDS (R11, +2.9),
//    two-kernel+LDS staging (R12, +3.9). Deltas are within the +/-3us
//    fill-noise band; R0's scalarized-uniform loop stands as best.
// ---------------------------------------------------------------------------

typedef float f32x2 __attribute__((ext_vector_type(2)));

static __device__ __forceinline__ f32x2 pk_fma(f32x2 a, f32x2 b, f32x2 c) {
    return __builtin_elementwise_fma(a, b, c);
}
static __device__ __forceinline__ f32x2 splat2(float v) {
    f32x2 r; r.x = v; r.y = v; return r;
}

#define INV_2PI 0.15915494309189535f

__global__ __launch_bounds__(64) void q_precompute(
    const float* __restrict__ theta,
    const float* __restrict__ W1,   // (8,32)
    const float* __restrict__ b1,   // (32,)
    const float* __restrict__ W2,   // (32,2)
    const float* __restrict__ b2,   // (2,)
    float* __restrict__ tab)
{
    __shared__ float Ure[8][8];
    __shared__ float Uim[8][8];
    const int t = threadIdx.x;

    if (t < 8) {
        float cr[8], ci[8];
        #pragma unroll
        for (int r = 0; r < 8; ++r) { cr[r] = (r == t) ? 1.f : 0.f; ci[r] = 0.f; }

        auto rxmix = [&](int a, int b, float c_, float s_) {   // RX pair
            float ar = cr[a], ai = ci[a], br = cr[b], bi = ci[b];
            cr[a] = c_*ar + s_*bi;   ci[a] = c_*ai - s_*br;
            cr[b] = s_*ai + c_*br;   ci[b] = -s_*ar + c_*bi;
        };
        auto rymix = [&](int a, int b, float c_, float s_) {   // RY pair
            float ar = cr[a], ai = ci[a], br = cr[b], bi = ci[b];
            cr[a] = c_*ar - s_*br;   ci[a] = c_*ai - s_*bi;
            cr[b] = s_*ar + c_*br;   ci[b] = s_*ai + c_*bi;
        };
        auto zmul = [&](int r, float u, float v) {             // row *= (u+iv)
            float xr = cr[r], xi = ci[r];
            cr[r] = xr*u - xi*v;  ci[r] = xr*v + xi*u;
        };
        // HW trig: revolutions; theta ~ N(0,1) so theta/2 is far inside range.
        auto hsin = [&](float a) { return __builtin_amdgcn_sinf(a * (0.5f*INV_2PI)); };
        auto hcos = [&](float a) { return __builtin_amdgcn_cosf(a * (0.5f*INV_2PI)); };

        float c, s;
        // index = 4*i0 + 2*i1 + i2  (wire0 = MSB)
        c = hcos(theta[0]); s = hsin(theta[0]);                 // RX wire0
        rxmix(0,4,c,s); rxmix(1,5,c,s); rxmix(2,6,c,s); rxmix(3,7,c,s);
        c = hcos(theta[1]); s = hsin(theta[1]);                 // RY wire1
        rymix(0,2,c,s); rymix(1,3,c,s); rymix(4,6,c,s); rymix(5,7,c,s);
        c = hcos(theta[2]); s = hsin(theta[2]);                 // RZ wire2
        #pragma unroll
        for (int r = 0; r < 8; ++r) zmul(r, c, (r & 1) ? s : -s);
        c = hcos(theta[3]); s = hsin(theta[3]);                 // CRX 0->1
        rxmix(4,6,c,s); rxmix(5,7,c,s);
        c = hcos(theta[4]); s = hsin(theta[4]);                 // RY wire2
        rymix(0,1,c,s); rymix(2,3,c,s); rymix(4,5,c,s); rymix(6,7,c,s);
        c = hcos(theta[5]); s = hsin(theta[5]);                 // RX wire1
        rxmix(0,2,c,s); rxmix(1,3,c,s); rxmix(4,6,c,s); rxmix(5,7,c,s);
        c = hcos(theta[6]); s = hsin(theta[6]);                 // CRX 1->2
        rxmix(2,3,c,s); rxmix(6,7,c,s);
        c = hcos(theta[7]); s = hsin(theta[7]);                 // RZ wire0
        #pragma unroll
        for (int r = 0; r < 8; ++r) zmul(r, c, (r < 4) ? -s : s);

        #pragma unroll
        for (int r = 0; r < 8; ++r) { Ure[r][t] = cr[r]; Uim[r][t] = ci[r]; }
    }
    __syncthreads();   // single wave: cheap

    if (t < 32) {
        // W[:,m] = U[:,col(m)] * phase, col = {0,2,4,6}, phase = {1,1,-i,-i}
        float Wre[8][4], Wim[8][4];
        #pragma unroll
        for (int j = 0; j < 8; ++j) {
            Wre[j][0] =  Ure[j][0]; Wim[j][0] =  Uim[j][0];
            Wre[j][1] =  Ure[j][2]; Wim[j][1] =  Uim[j][2];
            Wre[j][2] =  Uim[j][4]; Wim[j][2] = -Ure[j][4];
            Wre[j][3] =  Uim[j][6]; Wim[j][3] = -Ure[j][6];
        }
        float Q[4][4];
        #pragma unroll
        for (int m = 0; m < 4; ++m)
            #pragma unroll
            for (int n = 0; n < 4; ++n) Q[m][n] = 0.f;
        #pragma unroll
        for (int j = 0; j < 8; ++j) {
            float w = W1[j*32 + t];
            #pragma unroll
            for (int m = 0; m < 4; ++m)
                #pragma unroll
                for (int n = 0; n < 4; ++n)
                    Q[m][n] = fmaf(w, Wre[j][m]*Wre[j][n] + Wim[j][m]*Wim[j][n], Q[m][n]);
        }
        float R[3][3];
        R[0][0] = Q[0][0];
        R[0][1] = Q[0][1] + Q[1][0];
        R[0][2] = Q[1][1];
        R[1][0] = Q[0][2] + Q[2][0];
        R[1][1] = Q[0][3] + Q[1][2] + Q[2][1] + Q[3][0];
        R[1][2] = Q[1][3] + Q[3][1];
        R[2][0] = Q[2][2];
        R[2][1] = Q[2][3] + Q[3][2];
        R[2][2] = Q[3][3];
        float P[3][3];
        #pragma unroll
        for (int b = 0; b < 3; ++b) {
            P[0][b] = 0.5f*(R[0][b] + R[2][b]);
            P[1][b] = 0.5f*(R[0][b] - R[2][b]);
            P[2][b] = 0.5f*R[1][b];
        }
        float T[3][3];
        #pragma unroll
        for (int si = 0; si < 3; ++si) {
            T[si][0] = 0.5f*(P[si][0] + P[si][2]);
            T[si][1] = 0.5f*(P[si][0] - P[si][2]);
            T[si][2] = 0.5f*P[si][1];
        }
        float* row = tab + t*12;
        row[0] = T[0][1]; row[1] = T[0][2]; row[2] = T[1][0]; row[3] = T[2][0];
        row[4] = T[1][1]; row[5] = T[1][2]; row[6] = T[2][1]; row[7] = T[2][2];
        row[8] = b1[t] + T[0][0];
        row[9]  = W2[t*2+0];
        row[10] = W2[t*2+1];
        row[11] = 0.f;
    }
    if (t == 0) { tab[384] = b2[0]; tab[385] = b2[1]; tab[386] = 0.f; tab[387] = 0.f; }
}

__global__ __launch_bounds__(256) void q_main(
    const float* __restrict__ x,
    const float* __restrict__ tab,
    float* __restrict__ out,
    int B)
{
    const int lid = threadIdx.x;
    const int bb  = blockIdx.x * 2048;          // 8 elems/thread * 256 thr
    const int e0  = bb + lid;                   // element slot k: e0 + k*256

    const float b2a = tab[384], b2b = tab[385]; // uniform -> sgpr
    const float4* T4 = (const float4*)tab;      // uniform -> s_load_dwordx4

    if (bb + 2048 <= B) {
        // Coalesced: lane stride 12 B; x[:,2] bytes never requested.
        float xs0[8], xs1[8];
        #pragma unroll
        for (int k = 0; k < 8; ++k) {
            const int e = e0 + k*256;
            xs0[k] = x[e*3 + 0];
            xs1[k] = x[e*3 + 1];
        }

        // HW trig (revolutions; |x|<~6 rad in range). Group g = elems 2g,2g+1.
        f32x2 c0v[4], s0v[4], c1v[4], s1v[4], pcc[4], pcs[4], psc[4], pss[4];
        #pragma unroll
        for (int g = 0; g < 4; ++g) {
            #pragma unroll
            for (int j = 0; j < 2; ++j) {
                const int k = 2*g + j;
                const float r0 = xs0[k] * INV_2PI;
                const float r1 = xs1[k] * INV_2PI;
                s0v[g][j] = __builtin_amdgcn_sinf(r0);
                c0v[g][j] = __builtin_amdgcn_cosf(r0);
                s1v[g][j] = __builtin_amdgcn_sinf(r1);
                c1v[g][j] = __builtin_amdgcn_cosf(r1);
            }
            pcc[g] = c0v[g]*c1v[g]; pcs[g] = c0v[g]*s1v[g];
            psc[g] = s0v[g]*c1v[g]; pss[g] = s0v[g]*s1v[g];
        }

        f32x2 a0v[4], a1v[4];
        #pragma unroll
        for (int g = 0; g < 4; ++g) { a0v[g] = splat2(b2a); a1v[g] = splat2(b2b); }

        #pragma unroll 4
        for (int l = 0; l < 32; ++l) {
            const float4 cA = T4[l*3+0];   // T01 T02 T10 T20
            const float4 cB = T4[l*3+1];   // T11 T12 T21 T22
            const float4 cC = T4[l*3+2];   // bias w2a w2b pad
            #pragma unroll
            for (int g = 0; g < 4; ++g) {
                f32x2 h = pk_fma(splat2(cA.x), c1v[g], splat2(cC.x));
                h = pk_fma(splat2(cA.y), s1v[g], h);
                h = pk_fma(splat2(cA.z), c0v[g], h);
                h = pk_fma(splat2(cA.w), s0v[g], h);
                h = pk_fma(splat2(cB.x), pcc[g], h);
                h = pk_fma(splat2(cB.y), pcs[g], h);
                h = pk_fma(splat2(cB.z), psc[g], h);
                h = pk_fma(splat2(cB.w), pss[g], h);
                h = __builtin_elementwise_max(h, splat2(0.f));
                a0v[g] = pk_fma(h, splat2(cC.y), a0v[g]);
                a1v[g] = pk_fma(h, splat2(cC.z), a1v[g]);
            }
        }

        // Coalesced stores: one dwordx2 per element, lane stride 8 B.
        f32x2* O2 = (f32x2*)out;
        #pragma unroll
        for (int k = 0; k < 8; ++k) {
            const int e = e0 + k*256;
            f32x2 o; o.x = a0v[k>>1][k&1]; o.y = a1v[k>>1][k&1];
            O2[e] = o;
        }
    } else {
        // Tail block: per-element predicated scalar path.
        for (int k = 0; k < 8; ++k) {
            const int e = e0 + k*256;
            if (e >= B) continue;
            const float r0 = x[e*3+0] * INV_2PI;
            const float r1 = x[e*3+1] * INV_2PI;
            const float s0 = __builtin_amdgcn_sinf(r0), c0 = __builtin_amdgcn_cosf(r0);
            const float s1 = __builtin_amdgcn_sinf(r1), c1 = __builtin_amdgcn_cosf(r1);
            const float pc = c0*c1, ps = c0*s1, sc = s0*c1, ss = s0*s1;
            float A0 = b2a, A1 = b2b;
            for (int l = 0; l < 32; ++l) {
                const float4 cA = T4[l*3+0];
                const float4 cB = T4[l*3+1];
                const float4 cC = T4[l*3+2];
                float h = cC.x;
                h = fmaf(cA.x, c1, h);
                h = fmaf(cA.y, s1, h);
                h = fmaf(cA.z, c0, h);
                h = fmaf(cA.w, s0, h);
                h = fmaf(cB.x, pc, h);
                h = fmaf(cB.y, ps, h);
                h = fmaf(cB.z, sc, h);
                h = fmaf(cB.w, ss, h);
                h = fmaxf(h, 0.f);
                A0 = fmaf(h, cC.y, A0);
                A1 = fmaf(h, cC.z, A1);
            }
            out[e*2+0] = A0;
            out[e*2+1] = A1;
        }
    }
}

extern "C" void kernel_launch(void* const* d_in, const int* in_sizes, int n_in,
                              void* d_out, int out_size, void* d_ws, size_t ws_size,
                              hipStream_t stream) {
    const float* x     = (const float*)d_in[0];
    const float* theta = (const float*)d_in[1];
    const float* W1    = (const float*)d_in[2];
    const float* b1    = (const float*)d_in[3];
    const float* W2    = (const float*)d_in[4];
    const float* b2    = (const float*)d_in[5];
    float* out = (float*)d_out;
    float* tab = (float*)d_ws;

    const int B = in_sizes[0] / 3;

    q_precompute<<<1, 64, 0, stream>>>(theta, W1, b1, W2, b2, tab);

    const int blocks = (B + 2047) / 2048;       // 8 elems/thread * 256 thr
    q_main<<<blocks, 256, 0, stream>>>(x, tab, out, B);
}